// Round 1
// 159.373 us; speedup vs baseline: 1.0645x; 1.0645x over previous
//
#include <hip/hip_runtime.h>
#include <math.h>

#define DD 1024
#define HSZ 128
#define NB 4
#define TT 2048

typedef __attribute__((ext_vector_type(8))) short bf16x8;
typedef __attribute__((ext_vector_type(4))) float f32x4;

typedef __attribute__((address_space(3))) unsigned int lds_u32_t;
typedef __attribute__((address_space(1))) unsigned int glb_u32_t;

__device__ inline void gll16(const void* g, void* l) {
    __builtin_amdgcn_global_load_lds((const glb_u32_t*)g, (lds_u32_t*)l, 16, 0, 0);
}

__device__ inline unsigned short f2bf(float f){
    unsigned u = __builtin_bit_cast(unsigned, f);
    u += 0x7fff + ((u >> 16) & 1);
    return (unsigned short)(u >> 16);
}

// ---------------- k0: prep = RoPE table + frag-linear weight tiles ----------------
__global__ __launch_bounds__(256) void prep_kernel(
    const float* __restrict__ Wq, const float* __restrict__ Wk,
    const float* __restrict__ Wv, const float* __restrict__ Wo,
    unsigned short* __restrict__ Wbp, unsigned short* __restrict__ Wop,
    float2* __restrict__ tab)
{
    int bid = blockIdx.x, tid = threadIdx.x;
    if (bid < 512) {
        int i = bid * 256 + tid;
        int t = i >> 6, j = i & 63;
        float theta = __powf(10000.f, -(float)j * (1.f / 32.f));
        float ang = (float)t * theta;
        tab[i] = make_float2(__cosf(ang), __sinf(ang));
        return;
    }
    const float* s;
    unsigned short* dst;
    if (bid < 768) {
        int gc = (bid - 512) * 256 + tid;          // < 65536
        int tileid = gc >> 10;
        int ct = tileid >> 4, kk = tileid & 15;
        int ch = gc & 1023;
        int ns = ch >> 7, kc = (ch >> 6) & 1, l6 = ch & 63;
        int wrow = ct * 128 + ns * 16 + (l6 & 15);
        int kcol = kk * 64 + kc * 32 + (l6 >> 4) * 8;
        s = (wrow < 256) ? Wq + (size_t)wrow * DD
          : (wrow < 384) ? Wk + (size_t)(wrow - 256) * DD
                         : Wv + (size_t)(wrow - 384) * DD;
        s += kcol;
        dst = Wbp + (size_t)gc * 8;
    } else {
        int gc = (bid - 768) * 256 + tid;          // < 32768
        int tileid = gc >> 10;
        int ct = tileid >> 2, kk = tileid & 3;
        int ch = gc & 1023;
        int ns = ch >> 7, kc = (ch >> 6) & 1, l6 = ch & 63;
        int orow = ct * 128 + ns * 16 + (l6 & 15);
        int kcol = kk * 64 + kc * 32 + (l6 >> 4) * 8;
        s = Wo + (size_t)orow * 256 + kcol;
        dst = Wop + (size_t)gc * 8;
    }
    float4 a = ((const float4*)s)[0];
    float4 c = ((const float4*)s)[1];
    unsigned short o[8] = {f2bf(a.x),f2bf(a.y),f2bf(a.z),f2bf(a.w),
                           f2bf(c.x),f2bf(c.y),f2bf(c.z),f2bf(c.w)};
    *(uint4*)dst = *(const uint4*)o;
}

// ---------------- k1: QKV GEMM, 64x128 tiles, A direct-frag, B via global_load_lds ----
__global__ __launch_bounds__(256) void qkv_gemm_kernel(
    const float* __restrict__ x,
    const unsigned short* __restrict__ Wbp,
    const float2* __restrict__ tab,
    unsigned short* __restrict__ qo,
    unsigned short* __restrict__ Kp,
    unsigned short* __restrict__ Vp)
{
    int bid = blockIdx.x;
    int rt = bid & 127, ct = bid >> 7;
    int row0 = rt * 64;
    int b = row0 >> 11, t0 = row0 & (TT - 1);
    int tid = threadIdx.x;
    int wave = tid >> 6, lane = tid & 63;
    int mrow = lane & 15, quad = lane >> 4;

    __shared__ unsigned short Bs[2][8192];

    f32x4 acc[8];
    #pragma unroll
    for (int ns = 0; ns < 8; ++ns)
        #pragma unroll
        for (int r = 0; r < 4; ++r) acc[ns][r] = 0.f;

    const float* xrow = x + (size_t)(row0 + wave * 16 + mrow) * DD;

    {
        const unsigned short* wt = Wbp + (size_t)(ct * 16) * 8192;
        #pragma unroll
        for (int u = 0; u < 4; ++u)
            gll16(wt + (size_t)(u * 256 + tid) * 8, &Bs[0][(u * 256 + (tid & 192)) * 8]);
    }

    for (int kk = 0; kk < 16; ++kk) {
        __syncthreads();
        if (kk < 15) {
            const unsigned short* wt = Wbp + (size_t)(ct * 16 + kk + 1) * 8192;
            #pragma unroll
            for (int u = 0; u < 4; ++u)
                gll16(wt + (size_t)(u * 256 + tid) * 8, &Bs[(kk + 1) & 1][(u * 256 + (tid & 192)) * 8]);
        }
        bf16x8 af[2];
        #pragma unroll
        for (int kc = 0; kc < 2; ++kc) {
            const float* s = xrow + kk * 64 + kc * 32 + quad * 8;
            float4 f0 = ((const float4*)s)[0];
            float4 f1 = ((const float4*)s)[1];
            bf16x8 pk;
            pk[0]=(short)f2bf(f0.x); pk[1]=(short)f2bf(f0.y); pk[2]=(short)f2bf(f0.z); pk[3]=(short)f2bf(f0.w);
            pk[4]=(short)f2bf(f1.x); pk[5]=(short)f2bf(f1.y); pk[6]=(short)f2bf(f1.z); pk[7]=(short)f2bf(f1.w);
            af[kc] = pk;
        }
        const unsigned short* Bcur = Bs[kk & 1];
        #pragma unroll
        for (int kc = 0; kc < 2; ++kc)
            #pragma unroll
            for (int ns = 0; ns < 8; ++ns) {
                bf16x8 bb = *(const bf16x8*)(Bcur + ((ns * 2 + kc) * 64 + lane) * 8);
                acc[ns] = __builtin_amdgcn_mfma_f32_16x16x32_bf16(af[kc], bb, acc[ns], 0, 0, 0);
            }
    }

    __syncthreads();   // all waves done with Bs; safe to reuse for assembly

    if (ct < 2) {
        unsigned short* dst = qo + (size_t)(b * 2 + ct) * TT * HSZ;
        #pragma unroll
        for (int ns = 0; ns < 8; ++ns) {
            int colloc = ns * 16 + mrow;
            int pj = colloc >> 1;
            #pragma unroll
            for (int r = 0; r < 4; ++r) {
                int t = t0 + wave * 16 + quad * 4 + r;
                float v = acc[ns][r];
                float vp = __shfl_xor(v, 1, 64);
                float2 cs = tab[t * 64 + pj];
                float outv = ((mrow & 1) == 0) ? (v * cs.x - vp * cs.y)
                                               : (v * cs.x + vp * cs.y);
                dst[(size_t)t * HSZ + colloc] = f2bf(outv);
            }
        }
    } else if (ct == 2) {
        // K with RoPE -> K' frag-linear tile
        unsigned short* A_ = (unsigned short*)Bs;
        #pragma unroll
        for (int ns = 0; ns < 8; ++ns) {
            int colloc = ns * 16 + mrow;
            int pj = colloc >> 1;
            int chunk = (ns >> 1) * 4 + wave;
            int lph = (ns & 1) * 2 + (mrow >> 3);
            #pragma unroll
            for (int r = 0; r < 4; ++r) {
                int t = t0 + wave * 16 + quad * 4 + r;
                float v = acc[ns][r];
                float vp = __shfl_xor(v, 1, 64);
                float2 cs = tab[t * 64 + pj];
                float outv = ((mrow & 1) == 0) ? (v * cs.x - vp * cs.y)
                                               : (v * cs.x + vp * cs.y);
                A_[chunk * 512 + (lph * 16 + quad * 4 + r) * 8 + (mrow & 7)] = f2bf(outv);
            }
        }
        __syncthreads();
        unsigned short* kd = Kp + (size_t)(b * 32 + (t0 >> 6)) * 8192;
        #pragma unroll
        for (int u = 0; u < 4; ++u)
            *(uint4*)(kd + (u * 256 + tid) * 8) = *(const uint4*)(A_ + (u * 256 + tid) * 8);
    } else {
        // V -> V' frag-linear tile
        unsigned short* A_ = (unsigned short*)Bs;
        #pragma unroll
        for (int ns = 0; ns < 8; ++ns) {
            int chunk = ns * 2 + (wave >> 1);
            int lanep = ((wave & 1) * 2 + (quad >> 1)) * 16 + mrow;
            #pragma unroll
            for (int r = 0; r < 4; ++r)
                A_[chunk * 512 + lanep * 8 + (quad & 1) * 4 + r] = f2bf(acc[ns][r]);
        }
        __syncthreads();
        unsigned short* vd = Vp + (size_t)(b * 32 + (t0 >> 6)) * 8192;
        #pragma unroll
        for (int u = 0; u < 4; ++u)
            *(uint4*)(vd + (u * 256 + tid) * 8) = *(const uint4*)(A_ + (u * 256 + tid) * 8);
    }
}

// ---------------- k2: barrier-free flash attention ----------------
// Grid: 512 blocks = 64 q-tiles(32 rows) x 8 (b,h), largest tiles first.
// Each of the 4 waves handles j = wave, wave+4, ... independently:
//   K/V fragments read DIRECTLY from global (frag-linear Kp/Vp, L2-resident),
//   no K/V LDS staging, no per-iteration __syncthreads.
// Single end-of-kernel 4-way (m,l,O) merge through LDS.
__global__ __launch_bounds__(256, 2) void attn_mfma_kernel(
    const unsigned short* __restrict__ q,
    const unsigned short* __restrict__ Kp,
    const unsigned short* __restrict__ Vp,
    unsigned short* __restrict__ att)
{
    int bid = blockIdx.x;
    int qt = 63 - (bid >> 3);           // descending work: LPT schedule
    int bh = bid & 7;                   // bh in low bits: per-XCD K/V locality
    int b = bh >> 1, h = bh & 1;
    int q0 = qt * 32;
    int tid = threadIdx.x;
    int wave = tid >> 6, lane = tid & 63;
    int mrow = lane & 15, quad = lane >> 4;

    __shared__ char raw[66304];
    unsigned short* Psb = (unsigned short*)raw;        // [4][2048] shorts = 16KB (per-wave P transpose)
    float* Os  = (float*)(raw + 16384);                // 3 x 32x128 f32 = 48KB (merge)
    float* Ms_ = (float*)(raw + 65536);                // 96 floats
    float* Ls_ = Ms_ + 96;                             // 96 floats

    const unsigned short* qbase = q + (((size_t)(b * 2 + h)) * TT + q0 + mrow) * HSZ + quad * 8;
    bf16x8 qf[2][4];
    #pragma unroll
    for (int u = 0; u < 2; ++u)
        #pragma unroll
        for (int c = 0; c < 4; ++c)
            qf[u][c] = *(const bf16x8*)(qbase + u * 16 * HSZ + 32 * c);

    float mrun[2][4], lrun[2][4];
    f32x4 O[2][8];
    #pragma unroll
    for (int u = 0; u < 2; ++u) {
        #pragma unroll
        for (int r = 0; r < 4; ++r) { mrun[u][r] = -1e30f; lrun[u][r] = 0.f; }
        #pragma unroll
        for (int g = 0; g < 8; ++g)
            #pragma unroll
            for (int r = 0; r < 4; ++r) O[u][g][r] = 0.f;
    }

    const int NT = (qt >> 1) + 1;
    const float scl = 0.08838834764831845f;
    unsigned short* Pw = Psb + wave * 2048;

    for (int j = wave; j < NT; j += 4) {
        const unsigned short* Kt = Kp + (size_t)(b * 32 + j) * 8192;
        const unsigned short* Vt = Vp + (size_t)(b * 32 + j) * 8192;
        int s0 = j * 64;

        f32x4 S[2][4];
        #pragma unroll
        for (int u = 0; u < 2; ++u)
            #pragma unroll
            for (int f = 0; f < 4; ++f)
                #pragma unroll
                for (int r = 0; r < 4; ++r) S[u][f][r] = 0.f;

        #pragma unroll
        for (int c = 0; c < 4; ++c)
            #pragma unroll
            for (int f = 0; f < 4; ++f) {
                bf16x8 bk = *(const bf16x8*)(Kt + ((c * 4 + f) * 64 + lane) * 8);
                S[0][f] = __builtin_amdgcn_mfma_f32_16x16x32_bf16(qf[0][c], bk, S[0][f], 0, 0, 0);
                S[1][f] = __builtin_amdgcn_mfma_f32_16x16x32_bf16(qf[1][c], bk, S[1][f], 0, 0, 0);
            }

        if (j == NT - 1) {      // only the diagonal tile needs the causal mask
            #pragma unroll
            for (int u = 0; u < 2; ++u)
                #pragma unroll
                for (int f = 0; f < 4; ++f) {
                    int sg = s0 + 16 * f + mrow;
                    #pragma unroll
                    for (int r = 0; r < 4; ++r) {
                        int qg = q0 + u * 16 + quad * 4 + r;
                        S[u][f][r] = (sg <= qg) ? S[u][f][r] * scl : -1e30f;
                    }
                }
        } else {
            #pragma unroll
            for (int u = 0; u < 2; ++u)
                #pragma unroll
                for (int f = 0; f < 4; ++f)
                    #pragma unroll
                    for (int r = 0; r < 4; ++r) S[u][f][r] *= scl;
        }

        #pragma unroll
        for (int u = 0; u < 2; ++u) {
            float al[4];
            #pragma unroll
            for (int r = 0; r < 4; ++r) {
                float v = fmaxf(fmaxf(S[u][0][r], S[u][1][r]), fmaxf(S[u][2][r], S[u][3][r]));
                v = fmaxf(v, __shfl_xor(v, 1, 64));
                v = fmaxf(v, __shfl_xor(v, 2, 64));
                v = fmaxf(v, __shfl_xor(v, 4, 64));
                v = fmaxf(v, __shfl_xor(v, 8, 64));
                float mn = fmaxf(mrun[u][r], v);
                al[r] = __expf(mrun[u][r] - mn);
                mrun[u][r] = mn;
            }
            #pragma unroll
            for (int f = 0; f < 4; ++f)
                #pragma unroll
                for (int r = 0; r < 4; ++r)
                    S[u][f][r] = __expf(S[u][f][r] - mrun[u][r]);
            #pragma unroll
            for (int r = 0; r < 4; ++r) {
                float v = (S[u][0][r] + S[u][1][r]) + (S[u][2][r] + S[u][3][r]);
                v += __shfl_xor(v, 1, 64);
                v += __shfl_xor(v, 2, 64);
                v += __shfl_xor(v, 4, 64);
                v += __shfl_xor(v, 8, 64);
                lrun[u][r] = lrun[u][r] * al[r] + v;
            }
            #pragma unroll
            for (int g = 0; g < 8; ++g) {
                O[u][g][0] *= al[0]; O[u][g][1] *= al[1];
                O[u][g][2] *= al[2]; O[u][g][3] *= al[3];
            }
            // per-wave P transpose via LDS (verified frag mapping, no cross-wave sync)
            #pragma unroll
            for (int f = 0; f < 4; ++f) {
                int p = f >> 1;
                int hi2 = (2 * f + (mrow >> 3)) & 3;
                int jlo = mrow & 7;
                #pragma unroll
                for (int r = 0; r < 4; ++r)
                    Pw[u * 1024 + (p * 64 + hi2 * 16 + quad * 4 + r) * 8 + jlo] = f2bf(S[u][f][r]);
            }
        }

        bf16x8 pa[2][2];
        #pragma unroll
        for (int u = 0; u < 2; ++u)
            #pragma unroll
            for (int p = 0; p < 2; ++p)
                pa[u][p] = *(const bf16x8*)(Pw + u * 1024 + (p * 64 + lane) * 8);

        #pragma unroll
        for (int g = 0; g < 8; ++g)
            #pragma unroll
            for (int p = 0; p < 2; ++p) {
                bf16x8 bv = *(const bf16x8*)(Vt + ((g * 2 + p) * 64 + lane) * 8);
                O[0][g] = __builtin_amdgcn_mfma_f32_16x16x32_bf16(pa[0][p], bv, O[0][g], 0, 0, 0);
                O[1][g] = __builtin_amdgcn_mfma_f32_16x16x32_bf16(pa[1][p], bv, O[1][g], 0, 0, 0);
            }
    }

    // ---- 4-way merge (single barrier in the whole kernel) ----
    if (wave) {
        float* Ow = Os + (wave - 1) * 4096;
        #pragma unroll
        for (int u = 0; u < 2; ++u)
            #pragma unroll
            for (int g = 0; g < 8; ++g)
                #pragma unroll
                for (int r = 0; r < 4; ++r)
                    Ow[(u * 16 + quad * 4 + r) * 128 + g * 16 + mrow] = O[u][g][r];
        if (mrow == 0) {
            #pragma unroll
            for (int u = 0; u < 2; ++u)
                #pragma unroll
                for (int r = 0; r < 4; ++r) {
                    Ms_[(wave - 1) * 32 + u * 16 + quad * 4 + r] = mrun[u][r];
                    Ls_[(wave - 1) * 32 + u * 16 + quad * 4 + r] = lrun[u][r];
                }
        }
    }
    __syncthreads();
    if (wave == 0) {
        unsigned short* ab = att + (((size_t)b * TT + q0) * 2 + h) * 128;
        #pragma unroll
        for (int u = 0; u < 2; ++u) {
            float a0[4], a1[4], a2[4], a3[4], inv[4];
            #pragma unroll
            for (int r = 0; r < 4; ++r) {
                int row = u * 16 + quad * 4 + r;
                float m0 = mrun[u][r], l0 = lrun[u][r];
                float m1 = Ms_[row],      l1 = Ls_[row];
                float m2 = Ms_[32 + row], l2 = Ls_[32 + row];
                float m3 = Ms_[64 + row], l3 = Ls_[64 + row];
                float mM = fmaxf(fmaxf(m0, m1), fmaxf(m2, m3));
                a0[r] = __expf(m0 - mM); a1[r] = __expf(m1 - mM);
                a2[r] = __expf(m2 - mM); a3[r] = __expf(m3 - mM);
                inv[r] = 1.f / (l0 * a0[r] + l1 * a1[r] + l2 * a2[r] + l3 * a3[r]);
            }
            #pragma unroll
            for (int g = 0; g < 8; ++g)
                #pragma unroll
                for (int r = 0; r < 4; ++r) {
                    int row = u * 16 + quad * 4 + r;
                    float o = O[u][g][r] * a0[r]
                            + Os[row * 128 + g * 16 + mrow] * a1[r]
                            + Os[4096 + row * 128 + g * 16 + mrow] * a2[r]
                            + Os[8192 + row * 128 + g * 16 + mrow] * a3[r];
                    ab[(size_t)row * 256 + g * 16 + mrow] = f2bf(o * inv[r]);
                }
        }
    }
}

// ---------------- k3: outproj GEMM, A direct-frag from att, B via global_load_lds ----
__global__ __launch_bounds__(256) void outproj_gemm_kernel(
    const unsigned short* __restrict__ attb,
    const unsigned short* __restrict__ Wop,
    float* __restrict__ y)
{
    int bid = blockIdx.x;
    int rt = bid & 127, ct = bid >> 7;
    int row0 = rt * 64;
    int tid = threadIdx.x;
    int wave = tid >> 6, lane = tid & 63;
    int mrow = lane & 15, quad = lane >> 4;

    __shared__ unsigned short Bs[2][8192];

    f32x4 acc[8];
    #pragma unroll
    for (int ns = 0; ns < 8; ++ns)
        #pragma unroll
        for (int r = 0; r < 4; ++r) acc[ns][r] = 0.f;

    const unsigned short* arow = attb + (size_t)(row0 + wave * 16 + mrow) * 256;

    {
        const unsigned short* wt = Wop + (size_t)(ct * 4) * 8192;
        #pragma unroll
        for (int u = 0; u < 4; ++u)
            gll16(wt + (size_t)(u * 256 + tid) * 8, &Bs[0][(u * 256 + (tid & 192)) * 8]);
    }

    for (int kk = 0; kk < 4; ++kk) {
        __syncthreads();
        if (kk < 3) {
            const unsigned short* wt = Wop + (size_t)(ct * 4 + kk + 1) * 8192;
            #pragma unroll
            for (int u = 0; u < 4; ++u)
                gll16(wt + (size_t)(u * 256 + tid) * 8, &Bs[(kk + 1) & 1][(u * 256 + (tid & 192)) * 8]);
        }
        const unsigned short* Bcur = Bs[kk & 1];
        #pragma unroll
        for (int kc = 0; kc < 2; ++kc) {
            bf16x8 af = *(const bf16x8*)(arow + kk * 64 + kc * 32 + quad * 8);
            #pragma unroll
            for (int ns = 0; ns < 8; ++ns) {
                bf16x8 bb = *(const bf16x8*)(Bcur + ((ns * 2 + kc) * 64 + lane) * 8);
                acc[ns] = __builtin_amdgcn_mfma_f32_16x16x32_bf16(af, bb, acc[ns], 0, 0, 0);
            }
        }
    }

    #pragma unroll
    for (int ns = 0; ns < 8; ++ns)
        #pragma unroll
        for (int r = 0; r < 4; ++r) {
            int row = row0 + wave * 16 + quad * 4 + r;
            y[(size_t)row * DD + ct * 128 + ns * 16 + mrow] = acc[ns][r];
        }
}

extern "C" void kernel_launch(void* const* d_in, const int* in_sizes, int n_in,
                              void* d_out, int out_size, void* d_ws, size_t ws_size,
                              hipStream_t stream) {
    const float* x  = (const float*)d_in[0];
    const float* Wq = (const float*)d_in[1];
    const float* Wk = (const float*)d_in[2];
    const float* Wv = (const float*)d_in[3];
    const float* Wo = (const float*)d_in[4];
    float* y = (float*)d_out;

    // ws: att 4MB | qo 4MB | K' 2MB | V' 2MB | Wb' 1MB | Wo' 0.5MB | tab 1MB  (14.5MB)
    char* ws = (char*)d_ws;
    unsigned short* at  = (unsigned short*)(ws);
    unsigned short* qo  = (unsigned short*)(ws + 4u  * 1024 * 1024);
    unsigned short* Kp  = (unsigned short*)(ws + 8u  * 1024 * 1024);
    unsigned short* Vp  = (unsigned short*)(ws + 10u * 1024 * 1024);
    unsigned short* Wbp = (unsigned short*)(ws + 12u * 1024 * 1024);
    unsigned short* Wop = (unsigned short*)(ws + 13u * 1024 * 1024);
    float2*         tb  = (float2*)        (ws + 13824u * 1024);

    prep_kernel<<<896, 256, 0, stream>>>(Wq, Wk, Wv, Wo, Wbp, Wop, tb);
    qkv_gemm_kernel<<<512, 256, 0, stream>>>(x, Wbp, tb, qo, Kp, Vp);
    attn_mfma_kernel<<<512, 256, 0, stream>>>(qo, Kp, Vp, at);
    outproj_gemm_kernel<<<1024, 256, 0, stream>>>(at, Wop, y);
}